// Round 21
// baseline (304.014 us; speedup 1.0000x reference)
//
#include <hip/hip_runtime.h>

#define BB 64
#define TT 512
#define DD 1024
#define UU 128

// ---------------------------------------------------------------------------
// Kernel 1: K-split GEMM partials. 512 blocks (256 tiles x 2 K-halves) x 256
// thr, tile 128x128, BK=32, 8x8/thread, 2 blocks/CU. XOR-swizzled As;
// split-n W reads. A-tile register-prefetched (pa[4]); W-tile staged via
// ASYNC global_load_lds into a double-buffered Ws.
// ---------------------------------------------------------------------------
#define KS_BM 128
#define KS_BK 32

__device__ __forceinline__ void gload_lds16(const float* g, float* l) {
    __builtin_amdgcn_global_load_lds(
        (__attribute__((address_space(1))) void*)g,
        (__attribute__((address_space(3))) void*)l, 16, 0, 0);
}

__global__ __launch_bounds__(256, 2) void gemm_ksplit(const float* __restrict__ A,
                                                      const float* __restrict__ W,
                                                      float* __restrict__ P0,
                                                      float* __restrict__ P1) {
    __shared__ __align__(16) float As[KS_BK][KS_BM];      // 16 KB, col = r ^ ((k>>2)<<2)
    __shared__ __align__(16) float Ws[2][KS_BK][UU];      // 2 x 16 KB, row-major

    const int tid  = threadIdx.x;          // 0..255
    const int tile = blockIdx.x & 255;
    const int ks   = blockIdx.x >> 8;      // 0 or 1
    const int row0 = tile * KS_BM;
    const int kbase = ks * 512;
    float* P = ks ? P1 : P0;

    const int mi = tid >> 4;               // 0..15 -> m = 8mi..8mi+7
    const int ni = tid & 15;               // 0..15 -> n = {4ni..+3} u {64+4ni..+3}
    const int ac = tid & 7;                // A staging: k-quad 0..7
    const int ar = tid >> 3;               // A staging: row 0..31
    const int asw = ac << 2;

    float acc[8][8] = {};
    float4 pa[4];

#define KS_GLOADA(k0)                                                              \
    {                                                                              \
        _Pragma("unroll")                                                          \
        for (int p = 0; p < 4; ++p)                                                \
            pa[p] = *(const float4*)&A[(size_t)(row0 + ar + 32 * p) * DD + kbase + (k0) + ac * 4]; \
    }

#define KS_GSTOREA                                                                 \
    {                                                                              \
        _Pragma("unroll")                                                          \
        for (int p = 0; p < 4; ++p) {                                              \
            const int rs = (ar + 32 * p) ^ asw;                                    \
            As[ac * 4 + 0][rs] = pa[p].x;                                          \
            As[ac * 4 + 1][rs] = pa[p].y;                                          \
            As[ac * 4 + 2][rs] = pa[p].z;                                          \
            As[ac * 4 + 3][rs] = pa[p].w;                                          \
        }                                                                          \
    }

#define KS_WLDS(k0, buf)                                                           \
    {                                                                              \
        const float* gsrc = W + (size_t)(kbase + (k0)) * UU + tid * 4;             \
        float* ldst = &Ws[buf][0][0] + tid * 4;                                    \
        _Pragma("unroll")                                                          \
        for (int q = 0; q < 4; ++q)                                                \
            gload_lds16(gsrc + 1024 * q, ldst + 1024 * q);                         \
    }

#define KS_COMPUTE(buf)                                                            \
    {                                                                              \
        _Pragma("unroll 4")                                                        \
        for (int k = 0; k < KS_BK; ++k) {                                          \
            const int sw = (k >> 2) << 2;                                          \
            const float4 a0 = *(const float4*)&As[k][(mi * 8) ^ sw];               \
            const float4 a1 = *(const float4*)&As[k][(mi * 8 + 4) ^ sw];           \
            const float4 w0 = *(const float4*)&Ws[buf][k][ni * 4];                 \
            const float4 w1 = *(const float4*)&Ws[buf][k][64 + ni * 4];            \
            const float a[8] = {a0.x, a0.y, a0.z, a0.w, a1.x, a1.y, a1.z, a1.w};   \
            const float w[8] = {w0.x, w0.y, w0.z, w0.w, w1.x, w1.y, w1.z, w1.w};   \
            _Pragma("unroll")                                                      \
            for (int i = 0; i < 8; ++i)                                            \
                _Pragma("unroll")                                                  \
                for (int j = 0; j < 8; ++j) acc[i][j] = fmaf(a[i], w[j], acc[i][j]); \
        }                                                                          \
    }

    KS_WLDS(0, 0);
    KS_GLOADA(0);
    KS_GSTOREA;
    __syncthreads();
    int cur = 0;
    for (int k0 = KS_BK; k0 < 512; k0 += KS_BK) {
        KS_WLDS(k0, cur ^ 1);
        KS_GLOADA(k0);
        KS_COMPUTE(cur);
        __syncthreads();
        KS_GSTOREA;
        __syncthreads();
        cur ^= 1;
    }
    KS_COMPUTE(cur);

#pragma unroll
    for (int i = 0; i < 8; ++i) {
        const int row = row0 + mi * 8 + i;
        float4 o0, o1;
        o0.x = acc[i][0]; o0.y = acc[i][1]; o0.z = acc[i][2]; o0.w = acc[i][3];
        o1.x = acc[i][4]; o1.y = acc[i][5]; o1.z = acc[i][6]; o1.w = acc[i][7];
        *(float4*)&P[(size_t)row * UU + ni * 4] = o0;
        *(float4*)&P[(size_t)row * UU + 64 + ni * 4] = o1;
    }
}

// ---------------------------------------------------------------------------
// DPP / max3 helpers
// ---------------------------------------------------------------------------
#define DPPI(x, ctrl) __builtin_amdgcn_mov_dpp((x), (ctrl), 0xF, 0xF, true)
#define DPPF(x, ctrl) __int_as_float(DPPI(__float_as_int(x), (ctrl)))
// quad_perm xor1 = 0xB1, xor2 = 0x4E, row_shl:4 = 0x104

__device__ __forceinline__ float fmax3(float a, float b, float c) {
    float d;
    asm("v_max3_f32 %0, %1, %2, %3" : "=v"(d) : "v"(a), "v"(b), "v"(c));
    return d;
}
__device__ __forceinline__ float max16(const float* s) {
    const float g0 = fmax3(s[0], s[1], s[2]);
    const float g1 = fmax3(s[3], s[4], s[5]);
    const float g2 = fmax3(s[6], s[7], s[8]);
    const float g3 = fmax3(s[9], s[10], s[11]);
    const float g4 = fmax3(s[12], s[13], s[14]);
    return fmaxf(fmax3(g0, g1, g2), fmax3(g3, g4, s[15]));
}

// state padding: v -> v + 4*(v>>4); chunk bases 16B-aligned, disjoint bank quads.
__device__ __forceinline__ int SP16(int v) { return v + ((v >> 4) << 2); }

// ---------------------------------------------------------------------------
// Kernel 2: bidirectional value-only Viterbi, fused with the partial-sum:
// pot[t][u] = P0[t][u] + P1[t][u] + bias[u] computed during pot staging.
// 128 blocks x 1024 thr; u = tid>>3, h = tid&7 (16 v per lane), 3-level DPP.
// Blocks 0..63: fwd t=1..255 (hist -> P0 rows 0..255);
// blocks 64..127: bwd t=510..255 on q=pot+bwd (q hist -> P0 rows 256..511;
// bwd[255] stashed in out[b][0..127]).
// ---------------------------------------------------------------------------
__global__ __launch_bounds__(1024, 1) void fwdbwd_kernel(float* __restrict__ P0,
                                                         const float* __restrict__ P1,
                                                         const float* __restrict__ bias,
                                                         const float* __restrict__ chain,
                                                         float* __restrict__ out) {
    __shared__ __align__(16) float st[2][160];
    __shared__ __align__(16) float pot_lds[64][UU];   // 32 KB ring
    __shared__ __align__(16) float hist[32][UU];      // 16 KB history staging ring

    const bool isBwd = blockIdx.x >= BB;
    const int b = isBwd ? (blockIdx.x - BB) : blockIdx.x;
    const int tid = threadIdx.x;
    const int u = tid >> 3;    // output-state index, 0..127
    const int h = tid & 7;     // reduce-chunk index

    float* lg = P0 + (size_t)b * TT * UU;
    const float* p1 = P1 + (size_t)b * TT * UU;
    const float4* lg4 = (const float4*)lg;
    const float4* p14 = (const float4*)p1;
    const float4 bv4 = ((const float4*)bias)[tid & 31];
    float4* pot4 = (float4*)pot_lds;
    const float4* hist4 = (const float4*)hist;

#define POTSUM(f)                                                                  \
    ({ const float4 x_ = lg4[(f)]; const float4 y_ = p14[(f)];                     \
       float4 r_; r_.x = x_.x + y_.x + bv4.x; r_.y = x_.y + y_.y + bv4.y;          \
       r_.z = x_.z + y_.z + bv4.z; r_.w = x_.w + y_.w + bv4.w; r_; })

    float cr[16];
    if (!isBwd) {
#pragma unroll
        for (int j = 0; j < 16; ++j) cr[j] = chain[(size_t)(16 * h + j) * UU + u];
        for (int f = tid; f < 2048; f += 1024) pot4[f] = POTSUM(f);
        if (tid < UU) {
            const float v = lg[tid] + p1[tid] + bias[tid];
            st[0][SP16(tid)] = v;
            hist[0][tid] = v;
        }
    } else {
#pragma unroll
        for (int j = 0; j < 16; ++j) cr[j] = chain[(size_t)u * UU + 16 * h + j];
        for (int f = tid; f < 2048; f += 1024) pot4[f] = POTSUM(448 * 32 + f);
        if (tid < UU) {
            const size_t idx = (size_t)511 * UU + tid;
            const float v = lg[idx] + p1[idx] + bias[tid];
            st[0][SP16(tid)] = v;
            hist[31][tid] = v;
        }
    }
    __syncthreads();

    if (!isBwd) {
        auto step = [&](int tt, const float* stS, float* stD) {
            if ((tt & 15) == 0 && tid < 512) {   // flush rows tt-16..tt-1
                const int r0 = tt - 16;
                ((float4*)&lg[r0 * UU])[tid] = hist4[((r0 & 31) << 5) + tid];
            }
            if ((tt & 31) == 1 && tt > 1 && tt + 31 < 256) {
                const int f0 = (tt + 31) * 32 + tid;
                pot4[f0 & 2047] = POTSUM(f0);
            }
            const float4* sbp = (const float4*)(stS + 20 * h);
            const float4 sv0 = sbp[0], sv1 = sbp[1], sv2 = sbp[2], sv3 = sbp[3];
            const float a[16] = {sv0.x, sv0.y, sv0.z, sv0.w, sv1.x, sv1.y, sv1.z, sv1.w,
                                 sv2.x, sv2.y, sv2.z, sv2.w, sv3.x, sv3.y, sv3.z, sv3.w};
            float s[16];
#pragma unroll
            for (int j = 0; j < 16; ++j) s[j] = a[j] + cr[j];
            float m = max16(s);
            m = fmaxf(m, DPPF(m, 0xB1));
            m = fmaxf(m, DPPF(m, 0x4E));
            m = fmaxf(m, DPPF(m, 0x104));
            if (h == 0) {
                const float ns = pot_lds[tt & 63][u] + m;
                stD[SP16(u)] = ns;
                hist[tt & 31][u] = ns;
            }
            __syncthreads();
        };
        for (int t = 1; t < 255; t += 2) {
            step(t, st[0], st[1]);
            step(t + 1, st[1], st[0]);
        }
        step(255, st[0], st[1]);
        if (tid < 512) ((float4*)&lg[240 * UU])[tid] = hist4[(16 << 5) + tid];
    } else {
        auto stepB = [&](int t, const float* stS, float* stD) {
            if ((t & 15) == 15 && tid < 512) {   // flush rows t+1..t+16
                ((float4*)&lg[(t + 1) * UU])[tid] = hist4[(((t + 1) & 31) << 5) + tid];
            }
            if ((t & 31) == 31 && t >= 319) {    // stage rows t-63..t-32
                const int f0 = (t - 63) * 32 + tid;
                pot4[f0 & 2047] = POTSUM(f0);
            }
            const float4* sbp = (const float4*)(stS + 20 * h);
            const float4 sv0 = sbp[0], sv1 = sbp[1], sv2 = sbp[2], sv3 = sbp[3];
            const float a[16] = {sv0.x, sv0.y, sv0.z, sv0.w, sv1.x, sv1.y, sv1.z, sv1.w,
                                 sv2.x, sv2.y, sv2.z, sv2.w, sv3.x, sv3.y, sv3.z, sv3.w};
            float s[16];
#pragma unroll
            for (int j = 0; j < 16; ++j) s[j] = a[j] + cr[j];
            float m = max16(s);   // bwd[t][u]
            m = fmaxf(m, DPPF(m, 0xB1));
            m = fmaxf(m, DPPF(m, 0x4E));
            m = fmaxf(m, DPPF(m, 0x104));
            if (h == 0) {
                if (t >= 256) {
                    const float ns = pot_lds[t & 63][u] + m;   // q[t]
                    stD[SP16(u)] = ns;
                    hist[t & 31][u] = ns;
                } else {
                    out[(size_t)b * TT + u] = m;   // stash bwd[255]
                }
            }
            __syncthreads();
        };
        for (int t = 510; t > 255; t -= 2) {
            stepB(t, st[0], st[1]);
            stepB(t - 1, st[1], st[0]);
        }
    }
}

// ---------------------------------------------------------------------------
// Kernel 3: pointer recovery — fully parallel over (b, t). 1024 blocks
// (16 chunks of 32 t per batch) x 512 thr -> 4 blocks/CU, 32 waves/CU.
// c<8 : bp[t][u] = argmax_v(hist[t-1][v] + chain[v][u]),  t in 1..255
// c>=8: fp[r][v] = argmax_w(chain[v][w] + q[r][w]),       r in 256..511
// ---------------------------------------------------------------------------
#define MERGE2(bv, ba, ctrl)                                                      \
    {                                                                             \
        const float ov_ = DPPF((bv), ctrl); const int oa_ = DPPI((ba), ctrl);     \
        const bool tk_ = (ov_ > (bv)) || (ov_ == (bv) && oa_ < (ba));             \
        (bv) = tk_ ? ov_ : (bv); (ba) = tk_ ? oa_ : (ba);                         \
    }

__global__ __launch_bounds__(512) void ptr_kernel(const float* __restrict__ st_g,
                                                  const float* __restrict__ chain,
                                                  unsigned char* __restrict__ bp_g) {
    const int blk = blockIdx.x;
    const int b = blk >> 4;
    const int c = blk & 15;
    const int tid = threadIdx.x;
    const int g = tid >> 3;
    const int h = tid & 7;
    const int base = 16 * h;
    const bool isUp = (c >= 8);

    float cr0[16], cr1[16];
    if (!isUp) {
#pragma unroll
        for (int j = 0; j < 16; ++j) {
            cr0[j] = chain[(size_t)(base + j) * UU + 2 * g];
            cr1[j] = chain[(size_t)(base + j) * UU + 2 * g + 1];
        }
    } else {
#pragma unroll
        for (int j = 0; j < 16; ++j) {
            cr0[j] = chain[(size_t)(2 * g) * UU + base + j];
            cr1[j] = chain[(size_t)(2 * g + 1) * UU + base + j];
        }
    }

    const float* stb = st_g + (size_t)b * TT * UU;
    int t0, t1;
    if (!isUp) {
        t0 = (c == 0) ? 1 : c * 32;
        t1 = c * 32 + 32;
    } else {
        t0 = 256 + (c - 8) * 32;
        t1 = t0 + 32;
    }

    for (int t = t0; t < t1; ++t) {
        const int srow = isUp ? t : (t - 1);
        const float4* sp = (const float4*)(stb + (size_t)srow * UU + base);
        const float4 sv0 = sp[0], sv1 = sp[1], sv2 = sp[2], sv3 = sp[3];
        const float a[16] = {sv0.x, sv0.y, sv0.z, sv0.w, sv1.x, sv1.y, sv1.z, sv1.w,
                             sv2.x, sv2.y, sv2.z, sv2.w, sv3.x, sv3.y, sv3.z, sv3.w};

        float bv0, bv1;
        int ba0, ba1;
        {
            float vA = a[0] + cr0[0]; int iA = base;
            float vB = a[8] + cr0[8]; int iB = base + 8;
#pragma unroll
            for (int i = 1; i < 8; ++i) {
                const float tA = a[i] + cr0[i];
                const bool gA = tA > vA; vA = gA ? tA : vA; iA = gA ? base + i : iA;
                const float tB = a[8 + i] + cr0[8 + i];
                const bool gB = tB > vB; vB = gB ? tB : vB; iB = gB ? base + 8 + i : iB;
            }
            const bool gg = vB > vA;
            bv0 = gg ? vB : vA; ba0 = gg ? iB : iA;
        }
        {
            float vA = a[0] + cr1[0]; int iA = base;
            float vB = a[8] + cr1[8]; int iB = base + 8;
#pragma unroll
            for (int i = 1; i < 8; ++i) {
                const float tA = a[i] + cr1[i];
                const bool gA = tA > vA; vA = gA ? tA : vA; iA = gA ? base + i : iA;
                const float tB = a[8 + i] + cr1[8 + i];
                const bool gB = tB > vB; vB = gB ? tB : vB; iB = gB ? base + 8 + i : iB;
            }
            const bool gg = vB > vA;
            bv1 = gg ? vB : vA; ba1 = gg ? iB : iA;
        }
        MERGE2(bv0, ba0, 0xB1);  MERGE2(bv1, ba1, 0xB1);
        MERGE2(bv0, ba0, 0x4E);  MERGE2(bv1, ba1, 0x4E);
        MERGE2(bv0, ba0, 0x104); MERGE2(bv1, ba1, 0x104);

        if (h < 2) {
            const int v = 2 * g + h;
            bp_g[((size_t)b * TT + t) * UU + v] = (unsigned char)(h ? ba1 : ba0);
        }
    }
}

// ---------------------------------------------------------------------------
// Kernel 4: backtrace. 64 blocks x 512 thr.
// ---------------------------------------------------------------------------
__global__ __launch_bounds__(512) void backtrace_kernel(const float* __restrict__ st_g,
                                                        const unsigned char* __restrict__ bp_g,
                                                        float* __restrict__ out) {
    __shared__ unsigned char bp[TT][UU];   // 64 KB (row 0 unused)
    __shared__ unsigned char segmap[8][128];
    __shared__ int entryT[8];
    __shared__ int tags_i[TT];
    __shared__ int y255_s;

    const int b = blockIdx.x;
    const int tid = threadIdx.x;

    {
        const uint4* src = (const uint4*)(bp_g + (size_t)b * TT * UU);
        uint4* dst = (uint4*)bp;
#pragma unroll
        for (int i = 0; i < 8; ++i) dst[tid + 512 * i] = src[tid + 512 * i];
    }
    if (tid < 64) {
        const float* fw = st_g + ((size_t)b * TT + 255) * UU;
        const float* bw = out + (size_t)b * TT;
        float bv = fw[tid] + bw[tid];
        int bi = tid;
        const float v2 = fw[tid + 64] + bw[tid + 64];
        if (v2 > bv) { bv = v2; bi = tid + 64; }
#pragma unroll
        for (int d = 1; d < 64; d <<= 1) {
            const float ov = __shfl_xor(bv, d, 64);
            const int oi = __shfl_xor(bi, d, 64);
            if (ov > bv || (ov == bv && oi < bi)) { bv = ov; bi = oi; }
        }
        if (tid == 0) y255_s = bi;
    }
    __syncthreads();

    for (int w = tid; w < 8 * 128; w += 512) {
        const int seg = w >> 7;
        int tg = w & 127;
        if (seg < 4) {
            const int E = (seg == 3) ? 255 : 64 * (seg + 1);
            for (int t = E; t > 64 * seg; --t) tg = bp[t][tg];
        } else {
            const int B = 255 + 64 * (seg - 4);
            for (int r = B + 1; r <= B + 64; ++r) tg = bp[r][tg];
        }
        segmap[seg][w & 127] = (unsigned char)tg;
    }
    __syncthreads();

    if (tid == 0) {
        const int y255 = y255_s;
        entryT[3] = y255;
        entryT[2] = segmap[3][y255];
        entryT[1] = segmap[2][entryT[2]];
        entryT[0] = segmap[1][entryT[1]];
        entryT[4] = y255;
        entryT[5] = segmap[4][entryT[4]];
        entryT[6] = segmap[5][entryT[5]];
        entryT[7] = segmap[6][entryT[6]];
    }
    __syncthreads();

    if (tid < 8) {
        const int seg = tid;
        int tg = entryT[seg];
        if (seg < 4) {
            const int E = (seg == 3) ? 255 : 64 * (seg + 1);
            if (seg == 3) tags_i[255] = tg;
            for (int t = E; t > 64 * seg; --t) {
                tg = bp[t][tg];
                tags_i[t - 1] = tg;
            }
        } else {
            const int B = 255 + 64 * (seg - 4);
            for (int r = B + 1; r <= B + 64; ++r) {
                tg = bp[r][tg];
                tags_i[r] = tg;
            }
        }
    }
    __syncthreads();

    out[(size_t)b * TT + tid] = (float)tags_i[tid];
}

extern "C" void kernel_launch(void* const* d_in, const int* in_sizes, int n_in,
                              void* d_out, int out_size, void* d_ws, size_t ws_size,
                              hipStream_t stream) {
    const float* inputs = (const float*)d_in[0];
    const float* kern   = (const float*)d_in[1];
    const float* bias   = (const float*)d_in[2];
    const float* chain  = (const float*)d_in[3];

    const size_t LG = (size_t)BB * TT * UU * 4;    // 16.78 MB
    const size_t BP = (size_t)BB * TT * UU;        // 4.19 MB
    float* P0 = (float*)d_ws;                      // partials (k<512) -> st/q history
    unsigned char* bp = (unsigned char*)d_ws + LG;
    float* P1 = (float*)((unsigned char*)d_ws + LG + BP);   // partials (k>=512)
    float* out = (float*)d_out;

    gemm_ksplit<<<dim3(512), dim3(256), 0, stream>>>(inputs, kern, P0, P1);
    fwdbwd_kernel<<<dim3(2 * BB), dim3(1024), 0, stream>>>(P0, P1, bias, chain, out);
    ptr_kernel<<<dim3(BB * 16), dim3(512), 0, stream>>>(P0, chain, bp);
    backtrace_kernel<<<dim3(BB), dim3(512), 0, stream>>>(P0, bp, out);
}

// Round 22
// 300.741 us; speedup vs baseline: 1.0109x; 1.0109x over previous
//
#include <hip/hip_runtime.h>

#define BB 64
#define TT 512
#define DD 1024
#define UU 128

// ---------------------------------------------------------------------------
// Kernel 1: K-split GEMM partials. 512 blocks (256 tiles x 2 K-halves) x 256
// thr, tile 128x128, BK=32, 8x8/thread, 2 blocks/CU. XOR-swizzled As
// (double-buffered); split-n W reads. A-tile register-prefetched (pa[4]);
// W-tile staged via ASYNC global_load_lds into double-buffered Ws.
// ONE barrier per tile (both LDS operands double-buffered).
// ---------------------------------------------------------------------------
#define KS_BM 128
#define KS_BK 32

__device__ __forceinline__ void gload_lds16(const float* g, float* l) {
    __builtin_amdgcn_global_load_lds(
        (__attribute__((address_space(1))) void*)g,
        (__attribute__((address_space(3))) void*)l, 16, 0, 0);
}

__global__ __launch_bounds__(256, 2) void gemm_ksplit(const float* __restrict__ A,
                                                      const float* __restrict__ W,
                                                      float* __restrict__ P0,
                                                      float* __restrict__ P1) {
    __shared__ __align__(16) float As[2][KS_BK][KS_BM];   // 2 x 16 KB, col = r ^ ((k>>2)<<2)
    __shared__ __align__(16) float Ws[2][KS_BK][UU];      // 2 x 16 KB, row-major

    const int tid  = threadIdx.x;          // 0..255
    const int tile = blockIdx.x & 255;
    const int ks   = blockIdx.x >> 8;      // 0 or 1
    const int row0 = tile * KS_BM;
    const int kbase = ks * 512;
    float* P = ks ? P1 : P0;

    const int mi = tid >> 4;               // 0..15 -> m = 8mi..8mi+7
    const int ni = tid & 15;               // 0..15 -> n = {4ni..+3} u {64+4ni..+3}
    const int ac = tid & 7;                // A staging: k-quad 0..7
    const int ar = tid >> 3;               // A staging: row 0..31
    const int asw = ac << 2;

    float acc[8][8] = {};
    float4 pa[4];

#define KS_GLOADA(k0)                                                              \
    {                                                                              \
        _Pragma("unroll")                                                          \
        for (int p = 0; p < 4; ++p)                                                \
            pa[p] = *(const float4*)&A[(size_t)(row0 + ar + 32 * p) * DD + kbase + (k0) + ac * 4]; \
    }

#define KS_GSTOREA(buf)                                                            \
    {                                                                              \
        _Pragma("unroll")                                                          \
        for (int p = 0; p < 4; ++p) {                                              \
            const int rs = (ar + 32 * p) ^ asw;                                    \
            As[buf][ac * 4 + 0][rs] = pa[p].x;                                     \
            As[buf][ac * 4 + 1][rs] = pa[p].y;                                     \
            As[buf][ac * 4 + 2][rs] = pa[p].z;                                     \
            As[buf][ac * 4 + 3][rs] = pa[p].w;                                     \
        }                                                                          \
    }

#define KS_WLDS(k0, buf)                                                           \
    {                                                                              \
        const float* gsrc = W + (size_t)(kbase + (k0)) * UU + tid * 4;             \
        float* ldst = &Ws[buf][0][0] + tid * 4;                                    \
        _Pragma("unroll")                                                          \
        for (int q = 0; q < 4; ++q)                                                \
            gload_lds16(gsrc + 1024 * q, ldst + 1024 * q);                         \
    }

#define KS_COMPUTE(buf)                                                            \
    {                                                                              \
        _Pragma("unroll 4")                                                        \
        for (int k = 0; k < KS_BK; ++k) {                                          \
            const int sw = (k >> 2) << 2;                                          \
            const float4 a0 = *(const float4*)&As[buf][k][(mi * 8) ^ sw];          \
            const float4 a1 = *(const float4*)&As[buf][k][(mi * 8 + 4) ^ sw];      \
            const float4 w0 = *(const float4*)&Ws[buf][k][ni * 4];                 \
            const float4 w1 = *(const float4*)&Ws[buf][k][64 + ni * 4];            \
            const float a[8] = {a0.x, a0.y, a0.z, a0.w, a1.x, a1.y, a1.z, a1.w};   \
            const float w[8] = {w0.x, w0.y, w0.z, w0.w, w1.x, w1.y, w1.z, w1.w};   \
            _Pragma("unroll")                                                      \
            for (int i = 0; i < 8; ++i)                                            \
                _Pragma("unroll")                                                  \
                for (int j = 0; j < 8; ++j) acc[i][j] = fmaf(a[i], w[j], acc[i][j]); \
        }                                                                          \
    }

    KS_WLDS(0, 0);
    KS_GLOADA(0);
    KS_GSTOREA(0);
    __syncthreads();           // drains W(0) async; As[0] visible
    int cur = 0;
    for (int k0 = KS_BK; k0 < 512; k0 += KS_BK) {
        KS_WLDS(k0, cur ^ 1);  // async into other Ws buffer (reads of it finished pre-barrier)
        KS_GLOADA(k0);         // pa -> regs; lands during compute
        KS_COMPUTE(cur);
        KS_GSTOREA(cur ^ 1);   // tile k0 -> other As buffer (reads of it finished pre-barrier)
        __syncthreads();       // drains WLDS(k0); makes As[cur^1] visible
        cur ^= 1;
    }
    KS_COMPUTE(cur);

#pragma unroll
    for (int i = 0; i < 8; ++i) {
        const int row = row0 + mi * 8 + i;
        float4 o0, o1;
        o0.x = acc[i][0]; o0.y = acc[i][1]; o0.z = acc[i][2]; o0.w = acc[i][3];
        o1.x = acc[i][4]; o1.y = acc[i][5]; o1.z = acc[i][6]; o1.w = acc[i][7];
        *(float4*)&P[(size_t)row * UU + ni * 4] = o0;
        *(float4*)&P[(size_t)row * UU + 64 + ni * 4] = o1;
    }
}

// ---------------------------------------------------------------------------
// DPP / max3 helpers
// ---------------------------------------------------------------------------
#define DPPI(x, ctrl) __builtin_amdgcn_mov_dpp((x), (ctrl), 0xF, 0xF, true)
#define DPPF(x, ctrl) __int_as_float(DPPI(__float_as_int(x), (ctrl)))
// quad_perm xor1 = 0xB1, xor2 = 0x4E, row_shl:4 = 0x104

__device__ __forceinline__ float fmax3(float a, float b, float c) {
    float d;
    asm("v_max3_f32 %0, %1, %2, %3" : "=v"(d) : "v"(a), "v"(b), "v"(c));
    return d;
}
__device__ __forceinline__ float max16(const float* s) {
    const float g0 = fmax3(s[0], s[1], s[2]);
    const float g1 = fmax3(s[3], s[4], s[5]);
    const float g2 = fmax3(s[6], s[7], s[8]);
    const float g3 = fmax3(s[9], s[10], s[11]);
    const float g4 = fmax3(s[12], s[13], s[14]);
    return fmaxf(fmax3(g0, g1, g2), fmax3(g3, g4, s[15]));
}

// state padding: v -> v + 4*(v>>4); chunk bases 16B-aligned, disjoint bank quads.
__device__ __forceinline__ int SP16(int v) { return v + ((v >> 4) << 2); }

// ---------------------------------------------------------------------------
// Kernel 2: bidirectional value-only Viterbi, fused with the partial-sum:
// pot[t][u] = P0[t][u] + P1[t][u] + bias[u] computed during pot staging.
// 128 blocks x 1024 thr; u = tid>>3, h = tid&7 (16 v per lane), 3-level DPP.
// Blocks 0..63: fwd t=1..255 (hist -> P0 rows 0..255);
// blocks 64..127: bwd t=510..255 on q=pot+bwd (q hist -> P0 rows 256..511;
// bwd[255] stashed in out[b][0..127]).
// ---------------------------------------------------------------------------
__global__ __launch_bounds__(1024, 1) void fwdbwd_kernel(float* __restrict__ P0,
                                                         const float* __restrict__ P1,
                                                         const float* __restrict__ bias,
                                                         const float* __restrict__ chain,
                                                         float* __restrict__ out) {
    __shared__ __align__(16) float st[2][160];
    __shared__ __align__(16) float pot_lds[64][UU];   // 32 KB ring
    __shared__ __align__(16) float hist[32][UU];      // 16 KB history staging ring

    const bool isBwd = blockIdx.x >= BB;
    const int b = isBwd ? (blockIdx.x - BB) : blockIdx.x;
    const int tid = threadIdx.x;
    const int u = tid >> 3;    // output-state index, 0..127
    const int h = tid & 7;     // reduce-chunk index

    float* lg = P0 + (size_t)b * TT * UU;
    const float* p1 = P1 + (size_t)b * TT * UU;
    const float4* lg4 = (const float4*)lg;
    const float4* p14 = (const float4*)p1;
    const float4 bv4 = ((const float4*)bias)[tid & 31];
    float4* pot4 = (float4*)pot_lds;
    const float4* hist4 = (const float4*)hist;

#define POTSUM(f)                                                                  \
    ({ const float4 x_ = lg4[(f)]; const float4 y_ = p14[(f)];                     \
       float4 r_; r_.x = x_.x + y_.x + bv4.x; r_.y = x_.y + y_.y + bv4.y;          \
       r_.z = x_.z + y_.z + bv4.z; r_.w = x_.w + y_.w + bv4.w; r_; })

    float cr[16];
    if (!isBwd) {
#pragma unroll
        for (int j = 0; j < 16; ++j) cr[j] = chain[(size_t)(16 * h + j) * UU + u];
        for (int f = tid; f < 2048; f += 1024) pot4[f] = POTSUM(f);
        if (tid < UU) {
            const float v = lg[tid] + p1[tid] + bias[tid];
            st[0][SP16(tid)] = v;
            hist[0][tid] = v;
        }
    } else {
#pragma unroll
        for (int j = 0; j < 16; ++j) cr[j] = chain[(size_t)u * UU + 16 * h + j];
        for (int f = tid; f < 2048; f += 1024) pot4[f] = POTSUM(448 * 32 + f);
        if (tid < UU) {
            const size_t idx = (size_t)511 * UU + tid;
            const float v = lg[idx] + p1[idx] + bias[tid];
            st[0][SP16(tid)] = v;
            hist[31][tid] = v;
        }
    }
    __syncthreads();

    if (!isBwd) {
        auto step = [&](int tt, const float* stS, float* stD) {
            if ((tt & 15) == 0 && tid < 512) {   // flush rows tt-16..tt-1
                const int r0 = tt - 16;
                ((float4*)&lg[r0 * UU])[tid] = hist4[((r0 & 31) << 5) + tid];
            }
            if ((tt & 31) == 1 && tt > 1 && tt + 31 < 256) {
                const int f0 = (tt + 31) * 32 + tid;
                pot4[f0 & 2047] = POTSUM(f0);
            }
            const float4* sbp = (const float4*)(stS + 20 * h);
            const float4 sv0 = sbp[0], sv1 = sbp[1], sv2 = sbp[2], sv3 = sbp[3];
            const float a[16] = {sv0.x, sv0.y, sv0.z, sv0.w, sv1.x, sv1.y, sv1.z, sv1.w,
                                 sv2.x, sv2.y, sv2.z, sv2.w, sv3.x, sv3.y, sv3.z, sv3.w};
            float s[16];
#pragma unroll
            for (int j = 0; j < 16; ++j) s[j] = a[j] + cr[j];
            float m = max16(s);
            m = fmaxf(m, DPPF(m, 0xB1));
            m = fmaxf(m, DPPF(m, 0x4E));
            m = fmaxf(m, DPPF(m, 0x104));
            if (h == 0) {
                const float ns = pot_lds[tt & 63][u] + m;
                stD[SP16(u)] = ns;
                hist[tt & 31][u] = ns;
            }
            __syncthreads();
        };
        for (int t = 1; t < 255; t += 2) {
            step(t, st[0], st[1]);
            step(t + 1, st[1], st[0]);
        }
        step(255, st[0], st[1]);
        if (tid < 512) ((float4*)&lg[240 * UU])[tid] = hist4[(16 << 5) + tid];
    } else {
        auto stepB = [&](int t, const float* stS, float* stD) {
            if ((t & 15) == 15 && tid < 512) {   // flush rows t+1..t+16
                ((float4*)&lg[(t + 1) * UU])[tid] = hist4[(((t + 1) & 31) << 5) + tid];
            }
            if ((t & 31) == 31 && t >= 319) {    // stage rows t-63..t-32
                const int f0 = (t - 63) * 32 + tid;
                pot4[f0 & 2047] = POTSUM(f0);
            }
            const float4* sbp = (const float4*)(stS + 20 * h);
            const float4 sv0 = sbp[0], sv1 = sbp[1], sv2 = sbp[2], sv3 = sbp[3];
            const float a[16] = {sv0.x, sv0.y, sv0.z, sv0.w, sv1.x, sv1.y, sv1.z, sv1.w,
                                 sv2.x, sv2.y, sv2.z, sv2.w, sv3.x, sv3.y, sv3.z, sv3.w};
            float s[16];
#pragma unroll
            for (int j = 0; j < 16; ++j) s[j] = a[j] + cr[j];
            float m = max16(s);   // bwd[t][u]
            m = fmaxf(m, DPPF(m, 0xB1));
            m = fmaxf(m, DPPF(m, 0x4E));
            m = fmaxf(m, DPPF(m, 0x104));
            if (h == 0) {
                if (t >= 256) {
                    const float ns = pot_lds[t & 63][u] + m;   // q[t]
                    stD[SP16(u)] = ns;
                    hist[t & 31][u] = ns;
                } else {
                    out[(size_t)b * TT + u] = m;   // stash bwd[255]
                }
            }
            __syncthreads();
        };
        for (int t = 510; t > 255; t -= 2) {
            stepB(t, st[0], st[1]);
            stepB(t - 1, st[1], st[0]);
        }
    }
}

// ---------------------------------------------------------------------------
// Kernel 3: pointer recovery — fully parallel over (b, t). R20 form:
// 512 blocks (8 chunks of 64 t per batch) x 512 thr.
// c<4 : bp[t][u] = argmax_v(hist[t-1][v] + chain[v][u]),  t in 1..255
// c>=4: fp[r][v] = argmax_w(chain[v][w] + q[r][w]),       r in 256..511
// ---------------------------------------------------------------------------
#define MERGE2(bv, ba, ctrl)                                                      \
    {                                                                             \
        const float ov_ = DPPF((bv), ctrl); const int oa_ = DPPI((ba), ctrl);     \
        const bool tk_ = (ov_ > (bv)) || (ov_ == (bv) && oa_ < (ba));             \
        (bv) = tk_ ? ov_ : (bv); (ba) = tk_ ? oa_ : (ba);                         \
    }

__global__ __launch_bounds__(512) void ptr_kernel(const float* __restrict__ st_g,
                                                  const float* __restrict__ chain,
                                                  unsigned char* __restrict__ bp_g) {
    const int blk = blockIdx.x;
    const int b = blk >> 3;
    const int c = blk & 7;
    const int tid = threadIdx.x;
    const int g = tid >> 3;
    const int h = tid & 7;
    const int base = 16 * h;
    const bool isUp = (c >= 4);

    float cr0[16], cr1[16];
    if (!isUp) {
#pragma unroll
        for (int j = 0; j < 16; ++j) {
            cr0[j] = chain[(size_t)(base + j) * UU + 2 * g];
            cr1[j] = chain[(size_t)(base + j) * UU + 2 * g + 1];
        }
    } else {
#pragma unroll
        for (int j = 0; j < 16; ++j) {
            cr0[j] = chain[(size_t)(2 * g) * UU + base + j];
            cr1[j] = chain[(size_t)(2 * g + 1) * UU + base + j];
        }
    }

    const float* stb = st_g + (size_t)b * TT * UU;
    const int t0 = (c == 0) ? 1 : (c & 3) * 64 + (isUp ? 256 : 0);
    const int t1 = (c & 3) * 64 + 64 + (isUp ? 256 : 0);

    for (int t = t0; t < t1; ++t) {
        const int srow = isUp ? t : (t - 1);
        const float4* sp = (const float4*)(stb + (size_t)srow * UU + base);
        const float4 sv0 = sp[0], sv1 = sp[1], sv2 = sp[2], sv3 = sp[3];
        const float a[16] = {sv0.x, sv0.y, sv0.z, sv0.w, sv1.x, sv1.y, sv1.z, sv1.w,
                             sv2.x, sv2.y, sv2.z, sv2.w, sv3.x, sv3.y, sv3.z, sv3.w};

        float bv0, bv1;
        int ba0, ba1;
        {
            float vA = a[0] + cr0[0]; int iA = base;
            float vB = a[8] + cr0[8]; int iB = base + 8;
#pragma unroll
            for (int i = 1; i < 8; ++i) {
                const float tA = a[i] + cr0[i];
                const bool gA = tA > vA; vA = gA ? tA : vA; iA = gA ? base + i : iA;
                const float tB = a[8 + i] + cr0[8 + i];
                const bool gB = tB > vB; vB = gB ? tB : vB; iB = gB ? base + 8 + i : iB;
            }
            const bool gg = vB > vA;
            bv0 = gg ? vB : vA; ba0 = gg ? iB : iA;
        }
        {
            float vA = a[0] + cr1[0]; int iA = base;
            float vB = a[8] + cr1[8]; int iB = base + 8;
#pragma unroll
            for (int i = 1; i < 8; ++i) {
                const float tA = a[i] + cr1[i];
                const bool gA = tA > vA; vA = gA ? tA : vA; iA = gA ? base + i : iA;
                const float tB = a[8 + i] + cr1[8 + i];
                const bool gB = tB > vB; vB = gB ? tB : vB; iB = gB ? base + 8 + i : iB;
            }
            const bool gg = vB > vA;
            bv1 = gg ? vB : vA; ba1 = gg ? iB : iA;
        }
        MERGE2(bv0, ba0, 0xB1);  MERGE2(bv1, ba1, 0xB1);
        MERGE2(bv0, ba0, 0x4E);  MERGE2(bv1, ba1, 0x4E);
        MERGE2(bv0, ba0, 0x104); MERGE2(bv1, ba1, 0x104);

        if (h < 2) {
            const int v = 2 * g + h;
            bp_g[((size_t)b * TT + t) * UU + v] = (unsigned char)(h ? ba1 : ba0);
        }
    }
}

// ---------------------------------------------------------------------------
// Kernel 4: backtrace. 64 blocks x 512 thr.
// ---------------------------------------------------------------------------
__global__ __launch_bounds__(512) void backtrace_kernel(const float* __restrict__ st_g,
                                                        const unsigned char* __restrict__ bp_g,
                                                        float* __restrict__ out) {
    __shared__ unsigned char bp[TT][UU];   // 64 KB (row 0 unused)
    __shared__ unsigned char segmap[8][128];
    __shared__ int entryT[8];
    __shared__ int tags_i[TT];
    __shared__ int y255_s;

    const int b = blockIdx.x;
    const int tid = threadIdx.x;

    {
        const uint4* src = (const uint4*)(bp_g + (size_t)b * TT * UU);
        uint4* dst = (uint4*)bp;
#pragma unroll
        for (int i = 0; i < 8; ++i) dst[tid + 512 * i] = src[tid + 512 * i];
    }
    if (tid < 64) {
        const float* fw = st_g + ((size_t)b * TT + 255) * UU;
        const float* bw = out + (size_t)b * TT;
        float bv = fw[tid] + bw[tid];
        int bi = tid;
        const float v2 = fw[tid + 64] + bw[tid + 64];
        if (v2 > bv) { bv = v2; bi = tid + 64; }
#pragma unroll
        for (int d = 1; d < 64; d <<= 1) {
            const float ov = __shfl_xor(bv, d, 64);
            const int oi = __shfl_xor(bi, d, 64);
            if (ov > bv || (ov == bv && oi < bi)) { bv = ov; bi = oi; }
        }
        if (tid == 0) y255_s = bi;
    }
    __syncthreads();

    for (int w = tid; w < 8 * 128; w += 512) {
        const int seg = w >> 7;
        int tg = w & 127;
        if (seg < 4) {
            const int E = (seg == 3) ? 255 : 64 * (seg + 1);
            for (int t = E; t > 64 * seg; --t) tg = bp[t][tg];
        } else {
            const int B = 255 + 64 * (seg - 4);
            for (int r = B + 1; r <= B + 64; ++r) tg = bp[r][tg];
        }
        segmap[seg][w & 127] = (unsigned char)tg;
    }
    __syncthreads();

    if (tid == 0) {
        const int y255 = y255_s;
        entryT[3] = y255;
        entryT[2] = segmap[3][y255];
        entryT[1] = segmap[2][entryT[2]];
        entryT[0] = segmap[1][entryT[1]];
        entryT[4] = y255;
        entryT[5] = segmap[4][entryT[4]];
        entryT[6] = segmap[5][entryT[5]];
        entryT[7] = segmap[6][entryT[6]];
    }
    __syncthreads();

    if (tid < 8) {
        const int seg = tid;
        int tg = entryT[seg];
        if (seg < 4) {
            const int E = (seg == 3) ? 255 : 64 * (seg + 1);
            if (seg == 3) tags_i[255] = tg;
            for (int t = E; t > 64 * seg; --t) {
                tg = bp[t][tg];
                tags_i[t - 1] = tg;
            }
        } else {
            const int B = 255 + 64 * (seg - 4);
            for (int r = B + 1; r <= B + 64; ++r) {
                tg = bp[r][tg];
                tags_i[r] = tg;
            }
        }
    }
    __syncthreads();

    out[(size_t)b * TT + tid] = (float)tags_i[tid];
}

extern "C" void kernel_launch(void* const* d_in, const int* in_sizes, int n_in,
                              void* d_out, int out_size, void* d_ws, size_t ws_size,
                              hipStream_t stream) {
    const float* inputs = (const float*)d_in[0];
    const float* kern   = (const float*)d_in[1];
    const float* bias   = (const float*)d_in[2];
    const float* chain  = (const float*)d_in[3];

    const size_t LG = (size_t)BB * TT * UU * 4;    // 16.78 MB
    const size_t BP = (size_t)BB * TT * UU;        // 4.19 MB
    float* P0 = (float*)d_ws;                      // partials (k<512) -> st/q history
    unsigned char* bp = (unsigned char*)d_ws + LG;
    float* P1 = (float*)((unsigned char*)d_ws + LG + BP);   // partials (k>=512)
    float* out = (float*)d_out;

    gemm_ksplit<<<dim3(512), dim3(256), 0, stream>>>(inputs, kern, P0, P1);
    fwdbwd_kernel<<<dim3(2 * BB), dim3(1024), 0, stream>>>(P0, P1, bias, chain, out);
    ptr_kernel<<<dim3(BB * 8), dim3(512), 0, stream>>>(P0, chain, bp);
    backtrace_kernel<<<dim3(BB), dim3(512), 0, stream>>>(P0, bp, out);
}